// Round 1
// baseline (113.009 us; speedup 1.0000x reference)
//
#include <hip/hip_runtime.h>
#include <math.h>

// Problem constants (B,S,H) = (4,512,128), ALIGN_STRENGTH = 1.0
namespace {
constexpr int Bn = 4;
constexpr int Sn = 512;
constexpr int Hn = 128;
constexpr int ROWS = 8;                      // output rows per block
constexpr int NBLK = Bn * (Sn / ROWS);       // 256 blocks -> 1 per CU

__device__ inline float wave_sum(float v) {
    // full 64-lane butterfly reduction
    v += __shfl_xor(v, 32);
    v += __shfl_xor(v, 16);
    v += __shfl_xor(v, 8);
    v += __shfl_xor(v, 4);
    v += __shfl_xor(v, 2);
    v += __shfl_xor(v, 1);
    return v;
}
} // namespace

__global__ __launch_bounds__(128) void tsa_kernel(
    const float* __restrict__ x,   const float* __restrict__ ref,
    const float* __restrict__ Wa,  const float* __restrict__ Wb,
    const float* __restrict__ b1,  const float* __restrict__ W2,
    const float* __restrict__ b2,  const float* __restrict__ Wp1,
    const float* __restrict__ bp1, const float* __restrict__ Wp2,
    const float* __restrict__ bp2, float* __restrict__ out)
{
    const int k  = threadIdx.x;              // feature column 0..127
    const int b  = blockIdx.x >> 6;          // blockIdx / 64
    const int t0 = (blockIdx.x & 63) * ROWS; // first output row of this block

    const float* xbase = x   + (size_t)b * Sn * Hn;
    const float* rbase = ref + (size_t)b * Sn * Hn;

    // Row i in [0..ROWS] maps to global row g = t0-1+i (clamped at 0; the
    // clamped row's A values are only consumed by the t==0 copy path, which
    // ignores them).
    const int g0 = (t0 == 0) ? 0 : (t0 - 1);

    // Per-thread accumulators: a[k] for 9 rows, c[k] for 9 rows, hp[k] for 8.
    float aa[ROWS + 1], cc[ROWS + 1], hp[ROWS];
#pragma unroll
    for (int i = 0; i <= ROWS; ++i) { aa[i] = 0.f; cc[i] = 0.f; }
#pragma unroll
    for (int j = 0; j < ROWS; ++j) hp[j] = 0.f;

    // Main GEMV loop over the hidden/contraction dim h.
    // Weights: coalesced per-thread loads (thread k reads column k).
    // x/ref values: wave-uniform float4 broadcasts (L1-resident rows).
    for (int h = 0; h < Hn; h += 4) {
        float wa[4], wb[4], wp[4];
#pragma unroll
        for (int u = 0; u < 4; ++u) {
            wa[u] = Wa[(h + u) * Hn + k];
            wb[u] = Wb[(h + u) * Hn + k];
            wp[u] = Wp1[(h + u) * Hn + k];
        }
#pragma unroll
        for (int i = 0; i <= ROWS; ++i) {
            const int g = (i == 0) ? g0 : (t0 - 1 + i);
            const float4 xv = *(const float4*)(xbase + (size_t)g * Hn + h);
            const float4 rv = *(const float4*)(rbase + (size_t)g * Hn + h);
            aa[i] += xv.x * wa[0]; aa[i] += xv.y * wa[1];
            aa[i] += xv.z * wa[2]; aa[i] += xv.w * wa[3];
            cc[i] += rv.x * wb[0]; cc[i] += rv.y * wb[1];
            cc[i] += rv.z * wb[2]; cc[i] += rv.w * wb[3];
            if (i >= 1) {
                hp[i-1] += xv.x * wp[0]; hp[i-1] += xv.y * wp[1];
                hp[i-1] += xv.z * wp[2]; hp[i-1] += xv.w * wp[3];
            }
        }
    }

    const float b1k  = b1[k];
    const float w2k  = W2[k];
    const float bp1k = bp1[k];
    const float wq0  = Wp2[k * 3 + 0];
    const float wq1  = Wp2[k * 3 + 1];
    const float wq2  = Wp2[k * 3 + 2];

    __shared__ float part[ROWS][6][2];
    __shared__ float alphaA[ROWS];
    __shared__ int   opA[ROWS];

    const int wave = k >> 6;
    const int lane = k & 63;

    // 6 reductions per output row: diag / insert / delete dots for A, and the
    // 3 policy logits. A[b,i,j] = sigmoid(relu(a_i + c_j + b1) . W2 + b2).
#pragma unroll
    for (int j = 0; j < ROWS; ++j) {
        const float at   = aa[j + 1];  // a row t
        const float atm1 = aa[j];      // a row t-1
        const float ct   = cc[j + 1];  // c row t
        const float ctm1 = cc[j];      // c row t-1
        float vm = fmaxf(at   + ct   + b1k, 0.f) * w2k;  // A[t,t]
        float vi = fmaxf(atm1 + ct   + b1k, 0.f) * w2k;  // A[t-1,t]
        float vd = fmaxf(at   + ctm1 + b1k, 0.f) * w2k;  // A[t,t-1]
        const float hv = fmaxf(hp[j] + bp1k, 0.f);
        float l0 = hv * wq0, l1 = hv * wq1, l2 = hv * wq2;
        vm = wave_sum(vm); vi = wave_sum(vi); vd = wave_sum(vd);
        l0 = wave_sum(l0); l1 = wave_sum(l1); l2 = wave_sum(l2);
        if (lane == 0) {
            part[j][0][wave] = vm; part[j][1][wave] = vi; part[j][2][wave] = vd;
            part[j][3][wave] = l0; part[j][4][wave] = l1; part[j][5][wave] = l2;
        }
    }
    __syncthreads();

    // One thread per row finalizes: sigmoid, log_softmax, argmax(op), alpha.
    if (k < ROWS) {
        const float b2v = b2[0];
        const float sm = part[k][0][0] + part[k][0][1];
        const float si = part[k][1][0] + part[k][1][1];
        const float sd = part[k][2][0] + part[k][2][1];
        float l0 = part[k][3][0] + part[k][3][1] + bp2[0];
        float l1 = part[k][4][0] + part[k][4][1] + bp2[1];
        float l2 = part[k][5][0] + part[k][5][1] + bp2[2];
        const float Am = 1.f / (1.f + expf(-(sm + b2v)));
        const float Ai = 1.f / (1.f + expf(-(si + b2v)));
        const float Ad = 1.f / (1.f + expf(-(sd + b2v)));
        const float mx  = fmaxf(l0, fmaxf(l1, l2));
        const float lse = mx + logf(expf(l0 - mx) + expf(l1 - mx) + expf(l2 - mx));
        const float P0 = l0 - lse, P1 = l1 - lse, P2 = l2 - lse;
        const float s0 = Am * P0;   // match score
        const float s1 = Ai * P1;   // insert score
        const float s2 = Ad * P2;   // delete score
        // jnp.argmax: first occurrence of the max
        int op = 0; float best = s0;
        if (s1 > best) { op = 1; best = s1; }
        if (s2 > best) { op = 2; }
        opA[k]     = op;
        alphaA[k]  = Am;   // ALIGN_STRENGTH == 1.0
    }
    __syncthreads();

    // Output assembly: out[b,0] = x[b,0]; out[b,t] per selected op.
#pragma unroll
    for (int j = 0; j < ROWS; ++j) {
        const int t = t0 + j;
        float o;
        if (t == 0) {
            o = xbase[k];
        } else {
            const int   op = opA[j];
            const float al = alphaA[j];
            const float xt   = xbase[(size_t)t * Hn + k];
            const float rt   = rbase[(size_t)t * Hn + k];
            const float xtm1 = xbase[(size_t)(t - 1) * Hn + k];
            if (op == 0)      o = (1.f - al) * xt + al * rt;
            else if (op == 1) o = rt;
            else              o = xtm1;
        }
        out[((size_t)b * Sn + t) * Hn + k] = o;
    }
}

extern "C" void kernel_launch(void* const* d_in, const int* in_sizes, int n_in,
                              void* d_out, int out_size, void* d_ws, size_t ws_size,
                              hipStream_t stream) {
    const float* x    = (const float*)d_in[0];
    const float* ref  = (const float*)d_in[1];
    const float* Wa   = (const float*)d_in[2];
    const float* Wb   = (const float*)d_in[3];
    const float* b1   = (const float*)d_in[4];
    const float* W2   = (const float*)d_in[5];
    const float* b2   = (const float*)d_in[6];
    const float* Wp1  = (const float*)d_in[7];
    const float* bp1  = (const float*)d_in[8];
    const float* Wp2  = (const float*)d_in[9];
    const float* bp2  = (const float*)d_in[10];
    float* out = (float*)d_out;

    tsa_kernel<<<NBLK, 128, 0, stream>>>(x, ref, Wa, Wb, b1, W2, b2,
                                         Wp1, bp1, Wp2, bp2, out);
}

// Round 2
// 87.614 us; speedup vs baseline: 1.2899x; 1.2899x over previous
//
#include <hip/hip_runtime.h>
#include <math.h>

// Problem constants (B,S,H) = (4,512,128), ALIGN_STRENGTH = 1.0
namespace {
constexpr int Bn = 4;
constexpr int Sn = 512;
constexpr int Hn = 128;
constexpr int ROWS = 8;                      // output rows per block
constexpr int NBLK = Bn * (Sn / ROWS);       // 256 blocks -> 1 per CU
constexpr int NTHR = 512;                    // 4 groups x 128 threads (split-K)
constexpr int NACC = 2 * (ROWS + 1) + ROWS;  // 26 accumulators per (group,k)

__device__ inline float wave_sum(float v) {
    v += __shfl_xor(v, 32);
    v += __shfl_xor(v, 16);
    v += __shfl_xor(v, 8);
    v += __shfl_xor(v, 4);
    v += __shfl_xor(v, 2);
    v += __shfl_xor(v, 1);
    return v;
}
} // namespace

__global__ __launch_bounds__(NTHR) void tsa_kernel(
    const float* __restrict__ x,   const float* __restrict__ ref,
    const float* __restrict__ Wa,  const float* __restrict__ Wb,
    const float* __restrict__ b1,  const float* __restrict__ W2,
    const float* __restrict__ b2,  const float* __restrict__ Wp1,
    const float* __restrict__ bp1, const float* __restrict__ Wp2,
    const float* __restrict__ bp2, float* __restrict__ out)
{
    const int tid = threadIdx.x;
    const int k   = tid & 127;               // feature column 0..127
    const int grp = tid >> 7;                // split-K group 0..3
    const int b   = blockIdx.x >> 6;
    const int t0  = (blockIdx.x & 63) * ROWS;

    const float* xbase = x   + (size_t)b * Sn * Hn;
    const float* rbase = ref + (size_t)b * Sn * Hn;

    // Row i in [0..ROWS] maps to global row g = t0-1+i (clamped at 0; the
    // clamped row's A values only feed the t==0 copy path, which ignores them).
    const int g0 = (t0 == 0) ? 0 : (t0 - 1);

    // Partial accumulators over this group's h-chunk [grp*32, grp*32+32).
    float aa[ROWS + 1], cc[ROWS + 1], hp[ROWS];
#pragma unroll
    for (int i = 0; i <= ROWS; ++i) { aa[i] = 0.f; cc[i] = 0.f; }
#pragma unroll
    for (int j = 0; j < ROWS; ++j) hp[j] = 0.f;

    const int hbase = grp * 32;
#pragma unroll
    for (int h2 = 0; h2 < 32; h2 += 4) {
        const int h = hbase + h2;
        float wa[4], wb[4], wp[4];
#pragma unroll
        for (int u = 0; u < 4; ++u) {
            wa[u] = Wa[(h + u) * Hn + k];
            wb[u] = Wb[(h + u) * Hn + k];
            wp[u] = Wp1[(h + u) * Hn + k];
        }
#pragma unroll
        for (int i = 0; i <= ROWS; ++i) {
            const int g = (i == 0) ? g0 : (t0 - 1 + i);
            const float4 xv = *(const float4*)(xbase + (size_t)g * Hn + h);
            const float4 rv = *(const float4*)(rbase + (size_t)g * Hn + h);
            aa[i] += xv.x * wa[0]; aa[i] += xv.y * wa[1];
            aa[i] += xv.z * wa[2]; aa[i] += xv.w * wa[3];
            cc[i] += rv.x * wb[0]; cc[i] += rv.y * wb[1];
            cc[i] += rv.z * wb[2]; cc[i] += rv.w * wb[3];
            if (i >= 1) {
                hp[i-1] += xv.x * wp[0]; hp[i-1] += xv.y * wp[1];
                hp[i-1] += xv.z * wp[2]; hp[i-1] += xv.w * wp[3];
            }
        }
    }

    // LDS: partials [acc_idx][group][k]; after reduction the g=0 slot holds
    // the full sum.  26*512 floats = 53 KB.
    __shared__ float pacc[NACC * NTHR];
    __shared__ float alphaA[ROWS];
    __shared__ int   opA[ROWS];

#pragma unroll
    for (int i = 0; i <= ROWS; ++i) {
        pacc[i * NTHR + grp * 128 + k]            = aa[i];
        pacc[(ROWS + 1 + i) * NTHR + grp * 128 + k] = cc[i];
    }
#pragma unroll
    for (int j = 0; j < ROWS; ++j)
        pacc[(2 * (ROWS + 1) + j) * NTHR + grp * 128 + k] = hp[j];
    __syncthreads();

    // Cross-group reduce: each (acc,k) summed by exactly one thread into g=0.
    for (int idx = tid; idx < NACC * 128; idx += NTHR) {
        const int i = idx >> 7, kk = idx & 127;
        const float s = pacc[i * NTHR + kk]       + pacc[i * NTHR + 128 + kk] +
                        pacc[i * NTHR + 256 + kk] + pacc[i * NTHR + 384 + kk];
        pacc[i * NTHR + kk] = s;
    }
    __syncthreads();

    // Phase 2: wave w finalizes output row j = w (8 waves, 8 rows).
    // Lane l covers k = l and k = l+64.
    {
        const int j  = tid >> 6;   // 0..7
        const int ln = tid & 63;
        float vm = 0.f, vi = 0.f, vd = 0.f, l0 = 0.f, l1 = 0.f, l2 = 0.f;
#pragma unroll
        for (int half = 0; half < 2; ++half) {
            const int kk = ln + 64 * half;
            const float at   = pacc[(j + 1) * NTHR + kk];
            const float atm1 = pacc[j * NTHR + kk];
            const float ct   = pacc[(ROWS + 1 + j + 1) * NTHR + kk];
            const float ctm1 = pacc[(ROWS + 1 + j) * NTHR + kk];
            const float hvp  = pacc[(2 * (ROWS + 1) + j) * NTHR + kk];
            const float b1k = b1[kk], w2k = W2[kk], bp1k = bp1[kk];
            vm += fmaxf(at   + ct   + b1k, 0.f) * w2k;   // A[t,t]
            vi += fmaxf(atm1 + ct   + b1k, 0.f) * w2k;   // A[t-1,t]
            vd += fmaxf(at   + ctm1 + b1k, 0.f) * w2k;   // A[t,t-1]
            const float hv = fmaxf(hvp + bp1k, 0.f);
            l0 += hv * Wp2[kk * 3 + 0];
            l1 += hv * Wp2[kk * 3 + 1];
            l2 += hv * Wp2[kk * 3 + 2];
        }
        vm = wave_sum(vm); vi = wave_sum(vi); vd = wave_sum(vd);
        l0 = wave_sum(l0); l1 = wave_sum(l1); l2 = wave_sum(l2);
        if (ln == 0) {
            const float b2v = b2[0];
            const float Am = 1.f / (1.f + expf(-(vm + b2v)));
            const float Ai = 1.f / (1.f + expf(-(vi + b2v)));
            const float Ad = 1.f / (1.f + expf(-(vd + b2v)));
            float q0 = l0 + bp2[0], q1 = l1 + bp2[1], q2 = l2 + bp2[2];
            const float mx  = fmaxf(q0, fmaxf(q1, q2));
            const float lse = mx + logf(expf(q0 - mx) + expf(q1 - mx) + expf(q2 - mx));
            const float s0 = Am * (q0 - lse);   // match
            const float s1 = Ai * (q1 - lse);   // insert
            const float s2 = Ad * (q2 - lse);   // delete
            // jnp.argmax: first occurrence of the max
            int op = 0; float best = s0;
            if (s1 > best) { op = 1; best = s1; }
            if (s2 > best) { op = 2; }
            opA[j]    = op;
            alphaA[j] = Am;   // ALIGN_STRENGTH == 1.0
        }
    }
    __syncthreads();

    // Output assembly: 8 rows x 128 cols = 1024 elements, 2 per thread.
    for (int e = tid; e < ROWS * 128; e += NTHR) {
        const int j  = e >> 7;
        const int kk = e & 127;
        const int t  = t0 + j;
        float o;
        if (t == 0) {
            o = xbase[kk];
        } else {
            const int   op = opA[j];
            const float al = alphaA[j];
            const float xt   = xbase[(size_t)t * Hn + kk];
            const float rt   = rbase[(size_t)t * Hn + kk];
            const float xtm1 = xbase[(size_t)(t - 1) * Hn + kk];
            if (op == 0)      o = (1.f - al) * xt + al * rt;
            else if (op == 1) o = rt;
            else              o = xtm1;
        }
        out[((size_t)b * Sn + t) * Hn + kk] = o;
    }
}

extern "C" void kernel_launch(void* const* d_in, const int* in_sizes, int n_in,
                              void* d_out, int out_size, void* d_ws, size_t ws_size,
                              hipStream_t stream) {
    const float* x    = (const float*)d_in[0];
    const float* ref  = (const float*)d_in[1];
    const float* Wa   = (const float*)d_in[2];
    const float* Wb   = (const float*)d_in[3];
    const float* b1   = (const float*)d_in[4];
    const float* W2   = (const float*)d_in[5];
    const float* b2   = (const float*)d_in[6];
    const float* Wp1  = (const float*)d_in[7];
    const float* bp1  = (const float*)d_in[8];
    const float* Wp2  = (const float*)d_in[9];
    const float* bp2  = (const float*)d_in[10];
    float* out = (float*)d_out;

    tsa_kernel<<<NBLK, NTHR, 0, stream>>>(x, ref, Wa, Wb, b1, W2, b2,
                                          Wp1, bp1, Wp2, bp2, out);
}